// Round 2
// baseline (106.072 us; speedup 1.0000x reference)
//
#include <hip/hip_runtime.h>
#include <math.h>

// Problem constants (from reference setup_inputs)
constexpr int Bn = 4, Tn = 1000, Fn = 257, Cn = 6, Dn = 2048, On = 2;
constexpr int BTn = Bn * Tn;                      // 4000
constexpr double DEG2RAD = 0.017453292519943295;  // pi/180 in double

// Output segment offsets (in floats) within d_out
constexpr size_t OUT0_F = (size_t)BTn * Fn * Cn * 2;  // 12,336,000
constexpr size_t OUT1_F = (size_t)BTn * Fn * 2;       //  2,056,000
// out2 = BTn*Fn*On*2 = 4,112,000

// Workspace layout (bytes)
constexpr size_t TAB_BYTES  = (size_t)5 * Dn * sizeof(double);              // 81,920 (SoA [5][D])
constexpr size_t IND_BYTES  = 16384;                                        // 4000 ints, padded
constexpr size_t WTC_BYTES  = (size_t)Dn * Fn * Cn * 2 * sizeof(float);     // 25,264,128
constexpr size_t WTB_BYTES  = (size_t)Dn * Fn * On * 2 * sizeof(float);     //  8,421,376
constexpr size_t WS_NEEDED  = TAB_BYTES + IND_BYTES + 2 * WTC_BYTES + WTB_BYTES;

// ---------------------------------------------------------------------------
// K0: per-direction trig table in double (SoA: tab[j*Dn + d])
//   j=0: sin(d0/2)  j=1: cos(d0/2)  j=2: sin(d1/2)  j=3: cos(d1/2)  j=4: cos(d1)
// ---------------------------------------------------------------------------
__global__ __launch_bounds__(256) void build_dir_table(const float2* __restrict__ dirs,
                                                       double* __restrict__ tab) {
    int d = blockIdx.x * blockDim.x + threadIdx.x;
    if (d >= Dn) return;
    float2 dr = dirs[d];
    double d0 = (double)dr.x, d1 = (double)dr.y;
    tab[0 * Dn + d] = sin(0.5 * d0);
    tab[1 * Dn + d] = cos(0.5 * d0);
    tab[2 * Dn + d] = sin(0.5 * d1);
    tab[3 * Dn + d] = cos(0.5 * d1);
    tab[4 * Dn + d] = cos(d1);
}

// ---------------------------------------------------------------------------
// K1: argmin over direction codebook, one block per (b,t).
// Identical double arithmetic to R1 (which matched np exactly); wave shuffle
// reduce + single barrier instead of 8-step LDS tree.
// ---------------------------------------------------------------------------
__global__ __launch_bounds__(256) void argmin_dirs(const float* __restrict__ tdoa,
                                                   const double* __restrict__ tab,
                                                   int* __restrict__ ind) {
    const int bt = blockIdx.x;
    const int tid = threadIdx.x;

    double t0 = DEG2RAD * (double)tdoa[bt * 2 + 0];
    double t1 = DEG2RAD * (double)tdoa[bt * 2 + 1];
    double st0h = sin(0.5 * t0), ct0h = cos(0.5 * t0);
    double st1h = sin(0.5 * t1), ct1h = cos(0.5 * t1);
    double ct1 = cos(t1);
    double best = 1e300;
    int bidx = 0;
    #pragma unroll
    for (int k = 0; k < Dn / 256; ++k) {
        int d = tid + k * 256;
        // sin((t-d)/2) = sin(t/2)cos(d/2) - cos(t/2)sin(d/2)
        double s1 = st1h * tab[3 * Dn + d] - ct1h * tab[2 * Dn + d];
        double s2 = st0h * tab[1 * Dn + d] - ct0h * tab[0 * Dn + d];
        double a = s1 * s1 + ct1 * tab[4 * Dn + d] * (s2 * s2);
        if (a < best) { best = a; bidx = d; }  // ascending d per thread -> first-min kept
    }
    // wave-level lexicographic (val, idx) min
    #pragma unroll
    for (int off = 32; off > 0; off >>= 1) {
        double ov = __shfl_down(best, off);
        int oi = __shfl_down(bidx, off);
        if (ov < best || (ov == best && oi < bidx)) { best = ov; bidx = oi; }
    }
    __shared__ double swv[4];
    __shared__ int swi[4];
    if ((tid & 63) == 0) { swv[tid >> 6] = best; swi[tid >> 6] = bidx; }
    __syncthreads();
    if (tid == 0) {
        best = swv[0]; bidx = swi[0];
        #pragma unroll
        for (int w = 1; w < 4; ++w) {
            double v = swv[w]; int j = swi[w];
            if (v < best || (v == best && j < bidx)) { best = v; bidx = j; }
        }
        ind[bt] = bidx;
    }
}

// ---------------------------------------------------------------------------
// K2: transpose (real,imag) pair  src[CC,Fn,Dn] -> dst float2 [Dn][Fn][CC]
//   dst[(d*Fn + f)*CC + c] = {src_r[(c*Fn+f)*Dn + d], src_i[...]}
// Tiled: 48 rows (FB f-values x CC channels) x 64 d per block, LDS 48x65 float2.
// For CC=6, blockIdx.z selects between two (src,dst) pairs (wc / wd fused).
// ---------------------------------------------------------------------------
template <int CC>
__global__ __launch_bounds__(256) void transpose_w(const float* __restrict__ wr0,
                                                   const float* __restrict__ wi0,
                                                   float2* __restrict__ dst0,
                                                   const float* __restrict__ wr1,
                                                   const float* __restrict__ wi1,
                                                   float2* __restrict__ dst1) {
    constexpr int ROWS = 48;
    constexpr int FB = ROWS / CC;
    __shared__ float2 tile[ROWS][65];
    const int d0 = blockIdx.x * 64;
    const int f0 = blockIdx.y * FB;
    const int tid = threadIdx.x;
    const float* wr = (blockIdx.z == 0) ? wr0 : wr1;
    const float* wi = (blockIdx.z == 0) ? wi0 : wi1;
    float2* dst = (blockIdx.z == 0) ? dst0 : dst1;

    #pragma unroll
    for (int j = 0; j < (ROWS * 64) / 256; ++j) {
        int idx = j * 256 + tid;
        int r2 = idx >> 6;       // row in dst order: r2 = fi*CC + c
        int dl = idx & 63;
        int fi = r2 / CC, c = r2 % CC;
        int f = f0 + fi;
        if (f < Fn) {
            size_t s = (size_t)(c * Fn + f) * Dn + (size_t)(d0 + dl);
            tile[r2][dl] = make_float2(wr[s], wi[s]);
        }
    }
    __syncthreads();
    #pragma unroll
    for (int j = 0; j < (ROWS * 64) / 256; ++j) {
        int idx = j * 256 + tid;
        int dl = idx / ROWS;
        int r2 = idx % ROWS;
        int f = f0 + r2 / CC;
        if (f < Fn) {
            size_t o = (size_t)(d0 + dl) * Fn * CC + (size_t)f0 * CC + (size_t)r2;
            dst[o] = tile[r2][dl];
        }
    }
}

// ---------------------------------------------------------------------------
// K3: pure streaming gather+multiply. One thread per (bt,f); no barriers.
// ---------------------------------------------------------------------------
__global__ __launch_bounds__(256) void main_stream(
    const float* __restrict__ Xr, const float* __restrict__ Xi,
    const int* __restrict__ ind,
    const float* __restrict__ wTc, const float* __restrict__ wTd,
    const float* __restrict__ wTb,
    float2* __restrict__ out0, float2* __restrict__ out1, float4* __restrict__ out2) {
    const int idx = blockIdx.x * 256 + threadIdx.x;
    if (idx >= BTn * Fn) return;
    const int bt = idx / Fn;
    const int f = idx - bt * Fn;
    const int dsel = ind[bt];

    const float4* wc4 = (const float4*)(wTc + (size_t)dsel * Fn * Cn * 2) + f * 3;
    const float4* wd4 = (const float4*)(wTd + (size_t)dsel * Fn * Cn * 2) + f * 3;
    const float4* wb4 = (const float4*)(wTb + (size_t)dsel * Fn * On * 2) + f;
    const size_t base = (size_t)idx * Cn;  // complex-element base for X / out0

    float xr[Cn], xi[Cn];
    const float2* xr2 = (const float2*)(Xr + base);
    const float2* xi2 = (const float2*)(Xi + base);
    #pragma unroll
    for (int k = 0; k < Cn / 2; ++k) {
        float2 a = xr2[k]; xr[2 * k] = a.x; xr[2 * k + 1] = a.y;
        float2 b = xi2[k]; xi[2 * k] = b.x; xi[2 * k + 1] = b.y;
    }
    float4* o0 = (float4*)(out0 + base);  // base*8B is 48B-aligned -> 16B ok
    float accr = 0.f, acci = 0.f;
    #pragma unroll
    for (int k = 0; k < Cn / 2; ++k) {  // two complex per float4
        float4 wdv = wd4[k];
        float4 wcv = wc4[k];
        int c0 = 2 * k, c1 = 2 * k + 1;
        float4 r;
        r.x = wdv.x * xr[c0] - wdv.y * xi[c0];
        r.y = wdv.x * xi[c0] + wdv.y * xr[c0];
        r.z = wdv.z * xr[c1] - wdv.w * xi[c1];
        r.w = wdv.z * xi[c1] + wdv.w * xr[c1];
        o0[k] = r;
        accr += wcv.x * xr[c0] - wcv.y * xi[c0];
        acci += wcv.x * xi[c0] + wcv.y * xr[c0];
        accr += wcv.z * xr[c1] - wcv.w * xi[c1];
        acci += wcv.z * xi[c1] + wcv.w * xr[c1];
    }
    out1[idx] = make_float2(accr, acci);
    out2[idx] = wb4[0];  // both O channels, bit-exact copy
}

// K2': fallback (no workspace): direct strided gather, per-point double trig
__global__ __launch_bounds__(256) void main_direct(
    const float* __restrict__ Xr, const float* __restrict__ Xi,
    const float* __restrict__ tdoa, const float2* __restrict__ dirs,
    const float* __restrict__ wcr, const float* __restrict__ wci,
    const float* __restrict__ wdr, const float* __restrict__ wdi,
    const float* __restrict__ wbr, const float* __restrict__ wbi,
    float2* __restrict__ out0, float2* __restrict__ out1, float2* __restrict__ out2) {
    const int bt = blockIdx.x;
    const int tid = threadIdx.x;
    __shared__ double sv[256];
    __shared__ int si[256];

    double t0 = DEG2RAD * (double)tdoa[bt * 2 + 0];
    double t1 = DEG2RAD * (double)tdoa[bt * 2 + 1];
    double ct1 = cos(t1);
    double best = 1e300;
    int bidx = 0;
    for (int d = tid; d < Dn; d += 256) {
        float2 dr = dirs[d];
        double s1 = sin(0.5 * (t1 - (double)dr.y));
        double s2 = sin(0.5 * (t0 - (double)dr.x));
        double a = s1 * s1 + ct1 * cos((double)dr.y) * (s2 * s2);
        if (a < best) { best = a; bidx = d; }
    }
    sv[tid] = best; si[tid] = bidx;
    __syncthreads();
    for (int s = 128; s > 0; s >>= 1) {
        if (tid < s) {
            double v = sv[tid + s]; int j = si[tid + s];
            if (v < sv[tid] || (v == sv[tid] && j < si[tid])) { sv[tid] = v; si[tid] = j; }
        }
        __syncthreads();
    }
    const int dsel = si[0];
    const size_t base = (size_t)bt * Fn * Cn;

    for (int f = tid; f < Fn; f += 256) {
        const int fc = f * Cn;
        float accr = 0.f, acci = 0.f;
        #pragma unroll
        for (int c = 0; c < Cn; ++c) {
            float xr = Xr[base + fc + c], xi = Xi[base + fc + c];
            size_t wo = (size_t)(c * Fn + f) * Dn + dsel;
            float a_ = wdr[wo], b_ = wdi[wo];
            out0[base + fc + c] = make_float2(a_ * xr - b_ * xi, a_ * xi + b_ * xr);
            float p = wcr[wo], q = wci[wo];
            accr += p * xr - q * xi;
            acci += p * xi + q * xr;
        }
        out1[(size_t)bt * Fn + f] = make_float2(accr, acci);
        #pragma unroll
        for (int o = 0; o < On; ++o) {
            size_t wo = (size_t)(o * Fn + f) * Dn + dsel;
            out2[((size_t)bt * Fn + f) * On + o] = make_float2(wbr[wo], wbi[wo]);
        }
    }
}

extern "C" void kernel_launch(void* const* d_in, const int* in_sizes, int n_in,
                              void* d_out, int out_size, void* d_ws, size_t ws_size,
                              hipStream_t stream) {
    const float* Xr   = (const float*)d_in[0];
    const float* Xi   = (const float*)d_in[1];
    const float* tdoa = (const float*)d_in[2];
    const float2* dirs = (const float2*)d_in[3];
    const float* wcr = (const float*)d_in[4];
    const float* wci = (const float*)d_in[5];
    const float* wdr = (const float*)d_in[6];
    const float* wdi = (const float*)d_in[7];
    const float* wbr = (const float*)d_in[8];
    const float* wbi = (const float*)d_in[9];

    float* out = (float*)d_out;
    float2* out0 = (float2*)out;
    float2* out1 = (float2*)(out + OUT0_F);
    float2* out2f2 = (float2*)(out + OUT0_F + OUT1_F);
    float4* out2 = (float4*)(out + OUT0_F + OUT1_F);

    if (ws_size >= WS_NEEDED) {
        char* ws = (char*)d_ws;
        double* tab = (double*)ws;
        int* ind  = (int*)(ws + TAB_BYTES);
        float* wTc = (float*)(ws + TAB_BYTES + IND_BYTES);
        float* wTd = (float*)(ws + TAB_BYTES + IND_BYTES + WTC_BYTES);
        float* wTb = (float*)(ws + TAB_BYTES + IND_BYTES + 2 * WTC_BYTES);

        build_dir_table<<<Dn / 256, 256, 0, stream>>>(dirs, tab);
        argmin_dirs<<<BTn, 256, 0, stream>>>(tdoa, tab, ind);
        dim3 g6(Dn / 64, (Fn + 7) / 8, 2);   // 32 x 33 x 2 (wc + wd fused)
        dim3 g2(Dn / 64, (Fn + 23) / 24, 1); // 32 x 11
        transpose_w<6><<<g6, 256, 0, stream>>>(wcr, wci, (float2*)wTc,
                                               wdr, wdi, (float2*)wTd);
        transpose_w<2><<<g2, 256, 0, stream>>>(wbr, wbi, (float2*)wTb,
                                               wbr, wbi, (float2*)wTb);
        int total = BTn * Fn;
        main_stream<<<(total + 255) / 256, 256, 0, stream>>>(Xr, Xi, ind, wTc, wTd, wTb,
                                                             out0, out1, out2);
    } else {
        main_direct<<<BTn, 256, 0, stream>>>(Xr, Xi, tdoa, dirs,
                                             wcr, wci, wdr, wdi, wbr, wbi,
                                             out0, out1, out2f2);
    }
}

// Round 4
// 87.063 us; speedup vs baseline: 1.2183x; 1.2183x over previous
//
#include <hip/hip_runtime.h>
#include <math.h>

// Problem constants (from reference setup_inputs)
constexpr int Bn = 4, Tn = 1000, Fn = 257, Cn = 6, Dn = 2048, On = 2;
constexpr int BTn = Bn * Tn;                      // 4000
constexpr double DEG2RAD = 0.017453292519943295;  // pi/180 in double

// Output segment offsets (in floats) within d_out
constexpr size_t OUT0_F = (size_t)BTn * Fn * Cn * 2;  // 12,336,000
constexpr size_t OUT1_F = (size_t)BTn * Fn * 2;       //  2,056,000

// Derived sizes for the fused main kernel
constexpr int UNITS_PER_BT = Fn * Cn / 2;   // 771 complex-pairs (float4 units) per bt panel
constexpr int TOTAL_U = BTn * UNITS_PER_BT; // 3,084,000
constexpr int TOTAL_G = BTn * Fn;           // 1,028,000 f-groups
constexpr int UPB = 255;                    // u-units per block (85 f-groups)
constexpr int FPB = 85;

// Workspace layout (bytes)
constexpr size_t TAB_BYTES  = (size_t)4 * Dn * sizeof(double);              // 65,536 (SoA [4][D])
constexpr size_t IND_BYTES  = 16384;                                        // 4000 ints, padded
constexpr size_t WTC_BYTES  = (size_t)Dn * Fn * Cn * 2 * sizeof(float);     // 25,264,128
constexpr size_t WTB_BYTES  = (size_t)Dn * Fn * On * 2 * sizeof(float);     //  8,421,376
constexpr size_t WS_NEEDED  = TAB_BYTES + IND_BYTES + 2 * WTC_BYTES + WTB_BYTES;

// ---------------------------------------------------------------------------
// K0: per-direction trig table in double (SoA: tab[j*Dn + d])
//   j=0: cos(d0)  j=1: sin(d0)  j=2: cos(d1)  j=3: sin(d1)
// ---------------------------------------------------------------------------
__global__ __launch_bounds__(256) void build_dir_table(const float2* __restrict__ dirs,
                                                       double* __restrict__ tab) {
    int d = blockIdx.x * blockDim.x + threadIdx.x;
    if (d >= Dn) return;
    float2 dr = dirs[d];
    double d0 = (double)dr.x, d1 = (double)dr.y;
    tab[0 * Dn + d] = cos(d0);
    tab[1 * Dn + d] = sin(d0);
    tab[2 * Dn + d] = cos(d1);
    tab[3 * Dn + d] = sin(d1);
}

// ---------------------------------------------------------------------------
// K1: argmin over direction codebook.  250 blocks x 16 bt each; table cached
// in LDS once per block; one wave per bt scans 2048 dirs + shfl reduce.
// f64 full-angle identity: a2 = [1-cos(t1-d1)] + cos t1 cos d1 [1-cos(t0-d0)]
//                            = 2*a  (monotone in a, exact in reals).
// Lexicographic (val,idx) min == numpy first-occurrence argmin.
// ---------------------------------------------------------------------------
__global__ __launch_bounds__(256) void argmin_lds(const float* __restrict__ tdoa,
                                                  const double* __restrict__ tab,
                                                  int* __restrict__ ind) {
    __shared__ double s_cd0[Dn];
    __shared__ double s_sd0[Dn];
    __shared__ double s_cd1[Dn];
    __shared__ double s_sd1[Dn];
    const int t = threadIdx.x;
    #pragma unroll
    for (int k = 0; k < Dn / 256; ++k) {
        int d = t + 256 * k;
        s_cd0[d] = tab[0 * Dn + d];
        s_sd0[d] = tab[1 * Dn + d];
        s_cd1[d] = tab[2 * Dn + d];
        s_sd1[d] = tab[3 * Dn + d];
    }
    __syncthreads();
    const int w = t >> 6, lane = t & 63;
    #pragma unroll
    for (int s = 0; s < 4; ++s) {
        const int bt = blockIdx.x * 16 + w * 4 + s;
        double t0 = DEG2RAD * (double)tdoa[bt * 2 + 0];
        double t1 = DEG2RAD * (double)tdoa[bt * 2 + 1];
        double ct0 = cos(t0), st0 = sin(t0);
        double ct1 = cos(t1), st1 = sin(t1);
        double best = 1e300;
        int bidx = 0;
        for (int i = 0; i < Dn / 64; ++i) {
            int d = lane + 64 * i;  // ascending per lane -> first-min kept by strict <
            double u  = ct1 * s_cd1[d];
            double m1 = 1.0 - (u + st1 * s_sd1[d]);
            double m0 = 1.0 - (ct0 * s_cd0[d] + st0 * s_sd0[d]);
            double a  = m1 + u * m0;
            if (a < best) { best = a; bidx = d; }
        }
        #pragma unroll
        for (int off = 32; off > 0; off >>= 1) {
            double ov = __shfl_down(best, off);
            int oi = __shfl_down(bidx, off);
            if (ov < best || (ov == best && oi < bidx)) { best = ov; bidx = oi; }
        }
        if (lane == 0) ind[bt] = bidx;
    }
}

// ---------------------------------------------------------------------------
// K2: transpose (real,imag) pair  src[CC,Fn,Dn] -> dst float2 [Dn][Fn][CC]
//   dst2[(d*Fn + f)*CC + c] = {src_r[(c*Fn+f)*Dn + d], src_i[...]}
// float2 global reads along d, float4 global stores along (f,c).
// blockIdx.z selects between two (src,dst) pairs (wc / wd fused for CC=6).
// ---------------------------------------------------------------------------
template <int CC>
__global__ __launch_bounds__(256) void transpose_w(const float* __restrict__ wr0,
                                                   const float* __restrict__ wi0,
                                                   float2* __restrict__ dst0,
                                                   const float* __restrict__ wr1,
                                                   const float* __restrict__ wi1,
                                                   float2* __restrict__ dst1) {
    constexpr int ROWS = 48;           // fi*CC + c rows
    constexpr int FB = ROWS / CC;
    __shared__ float2 tile[ROWS][66];  // [row][d-local], padded
    const int d0 = blockIdx.x * 64;
    const int f0 = blockIdx.y * FB;
    const int tid = threadIdx.x;
    const float* wr = (blockIdx.z == 0) ? wr0 : wr1;
    const float* wi = (blockIdx.z == 0) ? wi0 : wi1;
    float2* dst = (blockIdx.z == 0) ? dst0 : dst1;

    // load phase: 48 rows x 32 float2 (64 d) = 1536 float2-loads over 6 iters
    #pragma unroll
    for (int j = 0; j < (ROWS * 32) / 256; ++j) {
        int idx = j * 256 + tid;
        int r2 = idx >> 5;        // row
        int dl2 = idx & 31;       // d-local / 2
        int f = f0 + r2 / CC;
        int c = r2 % CC;
        if (f < Fn) {
            const float2* sr = (const float2*)(wr + (size_t)(c * Fn + f) * Dn) + (d0 >> 1) + dl2;
            const float2* si = (const float2*)(wi + (size_t)(c * Fn + f) * Dn) + (d0 >> 1) + dl2;
            float2 vr = *sr, vi = *si;
            tile[r2][2 * dl2]     = make_float2(vr.x, vi.x);
            tile[r2][2 * dl2 + 1] = make_float2(vr.y, vi.y);
        }
    }
    __syncthreads();
    // store phase: 64 d x (ROWS/2) float4 = 1536 float4-stores over 6 iters
    constexpr int Q = ROWS / 2;
    const int rows_valid = (Fn - f0) * CC < ROWS ? (Fn - f0) * CC : ROWS;
    #pragma unroll
    for (int j = 0; j < (64 * Q) / 256; ++j) {
        int idx = j * 256 + tid;
        int dl = idx / Q;
        int q = idx % Q;
        if (2 * q + 1 < rows_valid) {
            float2 a = tile[2 * q][dl];
            float2 b = tile[2 * q + 1][dl];
            float4* o = (float4*)dst + (size_t)(d0 + dl) * (Fn * CC / 2) + (f0 * CC / 2) + q;
            *o = make_float4(a.x, a.y, b.x, b.y);
        }
    }
}

// ---------------------------------------------------------------------------
// K3: fused streaming kernel. Thread per complex-pair u (flat over [bt][f][c]):
//   out0 (elementwise wd*X), out1 (sum_c wc*X via 2KB LDS partials),
//   out2 (coalesced wTb panel copy) -- every global stream lane-contiguous.
// ---------------------------------------------------------------------------
__global__ __launch_bounds__(256) void main_fused(
    const float* __restrict__ Xr, const float* __restrict__ Xi,
    const int* __restrict__ ind,
    const float* __restrict__ wTc, const float* __restrict__ wTd,
    const float* __restrict__ wTb,
    float4* __restrict__ out0, float2* __restrict__ out1, float4* __restrict__ out2) {
    __shared__ float2 part[256];
    const int b = blockIdx.x;
    const int t = threadIdx.x;
    const unsigned u = (unsigned)b * UPB + (unsigned)t;
    const bool active = (t < UPB) && (u < (unsigned)TOTAL_U);
    float2 pacc = make_float2(0.f, 0.f);
    if (active) {
        unsigned bt = u / (unsigned)UNITS_PER_BT;
        unsigned off = u - bt * (unsigned)UNITS_PER_BT;
        int dsel = ind[bt];
        float4 wd = ((const float4*)wTd)[(size_t)dsel * UNITS_PER_BT + off];
        float4 wc = ((const float4*)wTc)[(size_t)dsel * UNITS_PER_BT + off];
        float2 xr = ((const float2*)Xr)[u];
        float2 xi = ((const float2*)Xi)[u];
        float4 r;
        r.x = wd.x * xr.x - wd.y * xi.x;
        r.y = wd.x * xi.x + wd.y * xr.x;
        r.z = wd.z * xr.y - wd.w * xi.y;
        r.w = wd.z * xi.y + wd.w * xr.y;
        out0[u] = r;
        pacc.x = (wc.x * xr.x - wc.y * xi.x) + (wc.z * xr.y - wc.w * xi.y);
        pacc.y = (wc.x * xi.x + wc.y * xr.x) + (wc.z * xi.y + wc.w * xr.y);
    }
    part[t] = pacc;
    __syncthreads();
    if (t < FPB) {
        unsigned G = (unsigned)b * FPB + (unsigned)t;
        if (G < (unsigned)TOTAL_G) {
            float2 a0 = part[3 * t], a1 = part[3 * t + 1], a2 = part[3 * t + 2];
            out1[G] = make_float2(a0.x + a1.x + a2.x, a0.y + a1.y + a2.y);
            unsigned bt2 = G / (unsigned)Fn;
            unsigned f2 = G - bt2 * (unsigned)Fn;
            int ds2 = ind[bt2];
            out2[G] = ((const float4*)wTb)[(size_t)ds2 * Fn + f2];
        }
    }
}

// Fallback (no workspace): direct strided gather, per-block argmin
__global__ __launch_bounds__(256) void main_direct(
    const float* __restrict__ Xr, const float* __restrict__ Xi,
    const float* __restrict__ tdoa, const float2* __restrict__ dirs,
    const float* __restrict__ wcr, const float* __restrict__ wci,
    const float* __restrict__ wdr, const float* __restrict__ wdi,
    const float* __restrict__ wbr, const float* __restrict__ wbi,
    float2* __restrict__ out0, float2* __restrict__ out1, float2* __restrict__ out2) {
    const int bt = blockIdx.x;
    const int tid = threadIdx.x;
    __shared__ double sv[256];
    __shared__ int si[256];

    double t0 = DEG2RAD * (double)tdoa[bt * 2 + 0];
    double t1 = DEG2RAD * (double)tdoa[bt * 2 + 1];
    double ct1 = cos(t1);
    double best = 1e300;
    int bidx = 0;
    for (int d = tid; d < Dn; d += 256) {
        float2 dr = dirs[d];
        double s1 = sin(0.5 * (t1 - (double)dr.y));
        double s2 = sin(0.5 * (t0 - (double)dr.x));
        double a = s1 * s1 + ct1 * cos((double)dr.y) * (s2 * s2);
        if (a < best) { best = a; bidx = d; }
    }
    sv[tid] = best; si[tid] = bidx;
    __syncthreads();
    for (int s = 128; s > 0; s >>= 1) {
        if (tid < s) {
            double v = sv[tid + s]; int j = si[tid + s];
            if (v < sv[tid] || (v == sv[tid] && j < si[tid])) { sv[tid] = v; si[tid] = j; }
        }
        __syncthreads();
    }
    const int dsel = si[0];
    const size_t base = (size_t)bt * Fn * Cn;

    for (int f = tid; f < Fn; f += 256) {
        const int fc = f * Cn;
        float accr = 0.f, acci = 0.f;
        #pragma unroll
        for (int c = 0; c < Cn; ++c) {
            float xr = Xr[base + fc + c], xi = Xi[base + fc + c];
            size_t wo = (size_t)(c * Fn + f) * Dn + dsel;
            float a_ = wdr[wo], b_ = wdi[wo];
            out0[base + fc + c] = make_float2(a_ * xr - b_ * xi, a_ * xi + b_ * xr);
            float p = wcr[wo], q = wci[wo];
            accr += p * xr - q * xi;
            acci += p * xi + q * xr;
        }
        out1[(size_t)bt * Fn + f] = make_float2(accr, acci);
        #pragma unroll
        for (int o = 0; o < On; ++o) {
            size_t wo = (size_t)(o * Fn + f) * Dn + dsel;
            out2[((size_t)bt * Fn + f) * On + o] = make_float2(wbr[wo], wbi[wo]);
        }
    }
}

extern "C" void kernel_launch(void* const* d_in, const int* in_sizes, int n_in,
                              void* d_out, int out_size, void* d_ws, size_t ws_size,
                              hipStream_t stream) {
    const float* Xr   = (const float*)d_in[0];
    const float* Xi   = (const float*)d_in[1];
    const float* tdoa = (const float*)d_in[2];
    const float2* dirs = (const float2*)d_in[3];
    const float* wcr = (const float*)d_in[4];
    const float* wci = (const float*)d_in[5];
    const float* wdr = (const float*)d_in[6];
    const float* wdi = (const float*)d_in[7];
    const float* wbr = (const float*)d_in[8];
    const float* wbi = (const float*)d_in[9];

    float* out = (float*)d_out;

    if (ws_size >= WS_NEEDED) {
        char* ws = (char*)d_ws;
        double* tab = (double*)ws;
        int* ind  = (int*)(ws + TAB_BYTES);
        float* wTc = (float*)(ws + TAB_BYTES + IND_BYTES);
        float* wTd = (float*)(ws + TAB_BYTES + IND_BYTES + WTC_BYTES);
        float* wTb = (float*)(ws + TAB_BYTES + IND_BYTES + 2 * WTC_BYTES);

        build_dir_table<<<Dn / 256, 256, 0, stream>>>(dirs, tab);
        argmin_lds<<<BTn / 16, 256, 0, stream>>>(tdoa, tab, ind);
        dim3 g6(Dn / 64, (Fn + 7) / 8, 2);   // 32 x 33 x 2 (wc + wd fused)
        dim3 g2(Dn / 64, (Fn + 23) / 24, 1); // 32 x 11
        transpose_w<6><<<g6, 256, 0, stream>>>(wcr, wci, (float2*)wTc,
                                               wdr, wdi, (float2*)wTd);
        transpose_w<2><<<g2, 256, 0, stream>>>(wbr, wbi, (float2*)wTb,
                                               wbr, wbi, (float2*)wTb);
        int grid = (TOTAL_U + UPB - 1) / UPB;  // 12,095
        main_fused<<<grid, 256, 0, stream>>>(Xr, Xi, ind, wTc, wTd, wTb,
                                             (float4*)out,
                                             (float2*)(out + OUT0_F),
                                             (float4*)(out + OUT0_F + OUT1_F));
    } else {
        main_direct<<<BTn, 256, 0, stream>>>(Xr, Xi, tdoa, dirs,
                                             wcr, wci, wdr, wdi, wbr, wbi,
                                             (float2*)out,
                                             (float2*)(out + OUT0_F),
                                             (float2*)(out + OUT0_F + OUT1_F));
    }
}

// Round 7
// 83.938 us; speedup vs baseline: 1.2637x; 1.0372x over previous
//
#include <hip/hip_runtime.h>
#include <math.h>

typedef float f4v __attribute__((ext_vector_type(4)));
typedef float f2v __attribute__((ext_vector_type(2)));

// Problem constants (from reference setup_inputs)
constexpr int Bn = 4, Tn = 1000, Fn = 257, Cn = 6, Dn = 2048, On = 2;
constexpr int BTn = Bn * Tn;                      // 4000
constexpr double DEG2RAD = 0.017453292519943295;  // pi/180 in double

// Output segment offsets (in floats) within d_out
constexpr size_t OUT0_F = (size_t)BTn * Fn * Cn * 2;  // 12,336,000
constexpr size_t OUT1_F = (size_t)BTn * Fn * 2;       //  2,056,000

// Derived sizes for the fused main kernel
constexpr int UNITS_PER_BT = Fn * Cn / 2;   // 771 complex-pairs (float4 units) per bt panel
constexpr int TOTAL_U = BTn * UNITS_PER_BT; // 3,084,000
constexpr int TOTAL_G = BTn * Fn;           // 1,028,000 f-groups
constexpr int UPB = 255;                    // u-units per block (85 f-groups)
constexpr int FPB = 85;

// Workspace layout (bytes)
constexpr size_t TAB_BYTES  = (size_t)4 * Dn * sizeof(double);              // 65,536 (SoA [4][D])
constexpr size_t BTT_BYTES  = (size_t)BTn * 4 * sizeof(double);             // 128,000 -> pad
constexpr size_t BTT_PAD    = 131072;
constexpr size_t IND_BYTES  = 16384;                                        // 4000 ints, padded
constexpr size_t WTC_BYTES  = (size_t)Dn * Fn * Cn * 2 * sizeof(float);     // 25,264,128
constexpr size_t WTB_BYTES  = (size_t)Dn * Fn * On * 2 * sizeof(float);     //  8,421,376
constexpr size_t WS_NEEDED  = TAB_BYTES + BTT_PAD + IND_BYTES + 2 * WTC_BYTES + WTB_BYTES;

// ---------------------------------------------------------------------------
// K0: trig tables in double.
//  dirs:  tab[j*Dn + d],  j=0: cos(d0)  j=1: sin(d0)  j=2: cos(d1)  j=3: sin(d1)
//  tdoa:  bttab[bt*4 + {0,1,2,3}] = cos(t0), sin(t0), cos(t1), sin(t1)
// Same double arithmetic as before (bit-identical inputs to the argmin).
// ---------------------------------------------------------------------------
__global__ __launch_bounds__(256) void build_tables(const float2* __restrict__ dirs,
                                                    const float* __restrict__ tdoa,
                                                    double* __restrict__ tab,
                                                    double* __restrict__ bttab) {
    int id = blockIdx.x * 256 + threadIdx.x;
    if (id < Dn) {
        float2 dr = dirs[id];
        double d0 = (double)dr.x, d1 = (double)dr.y;
        tab[0 * Dn + id] = cos(d0);
        tab[1 * Dn + id] = sin(d0);
        tab[2 * Dn + id] = cos(d1);
        tab[3 * Dn + id] = sin(d1);
    } else if (id < Dn + BTn) {
        int bt = id - Dn;
        double t0 = DEG2RAD * (double)tdoa[bt * 2 + 0];
        double t1 = DEG2RAD * (double)tdoa[bt * 2 + 1];
        bttab[bt * 4 + 0] = cos(t0);
        bttab[bt * 4 + 1] = sin(t0);
        bttab[bt * 4 + 2] = cos(t1);
        bttab[bt * 4 + 3] = sin(t1);
    }
}

// ---------------------------------------------------------------------------
// K1: argmin over direction codebook.  250 blocks x 16 bt each; table cached
// in LDS once per block; one wave per bt scans 2048 dirs + shfl reduce.
// Inner scan unrolled x4 so 12 ds_read_b64 are in flight per merge step.
// f64 identity: a2 = [1-cos(t1-d1)] + cos t1 cos d1 [1-cos(t0-d0)] = 2*a.
// Ascending-d strict-< merge == numpy first-occurrence argmin.
// ---------------------------------------------------------------------------
__global__ __launch_bounds__(256) void argmin_lds(const double* __restrict__ bttab,
                                                  const double* __restrict__ tab,
                                                  int* __restrict__ ind) {
    __shared__ double s_cd0[Dn];
    __shared__ double s_sd0[Dn];
    __shared__ double s_cd1[Dn];
    __shared__ double s_sd1[Dn];
    const int t = threadIdx.x;
    #pragma unroll
    for (int k = 0; k < Dn / 256; ++k) {
        int d = t + 256 * k;
        s_cd0[d] = tab[0 * Dn + d];
        s_sd0[d] = tab[1 * Dn + d];
        s_cd1[d] = tab[2 * Dn + d];
        s_sd1[d] = tab[3 * Dn + d];
    }
    __syncthreads();
    const int w = t >> 6, lane = t & 63;
    #pragma unroll
    for (int s = 0; s < 4; ++s) {
        const int bt = blockIdx.x * 16 + w * 4 + s;
        double ct0 = bttab[bt * 4 + 0], st0 = bttab[bt * 4 + 1];
        double ct1 = bttab[bt * 4 + 2], st1 = bttab[bt * 4 + 3];
        double best = 1e300;
        int bidx = 0;
        for (int i = 0; i < Dn / 256; ++i) {       // 8 outer iters
            const int d0 = lane + 256 * i;
            double a[4];
            #pragma unroll
            for (int k = 0; k < 4; ++k) {          // 12 independent LDS loads batched
                int d = d0 + 64 * k;
                double u  = ct1 * s_cd1[d];
                double m1 = 1.0 - (u + st1 * s_sd1[d]);
                double m0 = 1.0 - (ct0 * s_cd0[d] + st0 * s_sd0[d]);
                a[k] = m1 + u * m0;
            }
            #pragma unroll
            for (int k = 0; k < 4; ++k) {          // ascending-d merge keeps first-min
                int d = d0 + 64 * k;
                if (a[k] < best) { best = a[k]; bidx = d; }
            }
        }
        #pragma unroll
        for (int off = 32; off > 0; off >>= 1) {
            double ov = __shfl_down(best, off);
            int oi = __shfl_down(bidx, off);
            if (ov < best || (ov == best && oi < bidx)) { best = ov; bidx = oi; }
        }
        if (lane == 0) ind[bt] = bidx;
    }
}

// ---------------------------------------------------------------------------
// K2: transpose (real,imag) pair  src[CC,Fn,Dn] -> dst float2 [Dn][Fn][CC]
//   dst2[(d*Fn + f)*CC + c] = {src_r[(c*Fn+f)*Dn + d], src_i[...]}
// float4 nontemporal global reads along d, float4 global stores along (f,c).
// blockIdx.z selects between two (src,dst) pairs (wc / wd fused for CC=6).
// ---------------------------------------------------------------------------
template <int CC>
__global__ __launch_bounds__(256) void transpose_w(const float* __restrict__ wr0,
                                                   const float* __restrict__ wi0,
                                                   float2* __restrict__ dst0,
                                                   const float* __restrict__ wr1,
                                                   const float* __restrict__ wi1,
                                                   float2* __restrict__ dst1) {
    constexpr int ROWS = 48;           // fi*CC + c rows
    constexpr int FB = ROWS / CC;
    __shared__ f2v tile[ROWS][66];     // [row][d-local], padded (row = 528B, f4-aligned)
    const int d0 = blockIdx.x * 64;
    const int f0 = blockIdx.y * FB;
    const int tid = threadIdx.x;
    const float* wr = (blockIdx.z == 0) ? wr0 : wr1;
    const float* wi = (blockIdx.z == 0) ? wi0 : wi1;
    float2* dst = (blockIdx.z == 0) ? dst0 : dst1;

    // load phase: 48 rows x 16 float4 (64 d) per buffer -> 3 iters of 256
    #pragma unroll
    for (int j = 0; j < (ROWS * 16) / 256; ++j) {
        int idx = j * 256 + tid;
        int r2 = idx >> 4;        // row
        int q4 = idx & 15;        // float4 index along d
        int f = f0 + r2 / CC;
        int c = r2 % CC;
        if (f < Fn) {
            const f4v* sr = (const f4v*)(wr + (size_t)(c * Fn + f) * Dn + d0) + q4;
            const f4v* si = (const f4v*)(wi + (size_t)(c * Fn + f) * Dn + d0) + q4;
            f4v vr = __builtin_nontemporal_load(sr);
            f4v vi = __builtin_nontemporal_load(si);
            f4v* trow = (f4v*)&tile[r2][0];
            f4v lo = {vr[0], vi[0], vr[1], vi[1]};
            f4v hi = {vr[2], vi[2], vr[3], vi[3]};
            trow[2 * q4]     = lo;
            trow[2 * q4 + 1] = hi;
        }
    }
    __syncthreads();
    // store phase: 64 d x (ROWS/2) float4 = 6 iters of 256
    constexpr int Q = ROWS / 2;
    const int rows_valid = (Fn - f0) * CC < ROWS ? (Fn - f0) * CC : ROWS;
    #pragma unroll
    for (int j = 0; j < (64 * Q) / 256; ++j) {
        int idx = j * 256 + tid;
        int dl = idx / Q;
        int q = idx % Q;
        if (2 * q + 1 < rows_valid) {
            f2v a = tile[2 * q][dl];
            f2v b = tile[2 * q + 1][dl];
            f4v o = {a[0], a[1], b[0], b[1]};
            f4v* op = (f4v*)((float4*)dst + (size_t)(d0 + dl) * (Fn * CC / 2) + (f0 * CC / 2) + q);
            *op = o;   // cached: re-read by main_fused
        }
    }
}

// ---------------------------------------------------------------------------
// K3: fused streaming kernel. Thread per complex-pair u (flat over [bt][f][c]):
//   out0 (elementwise wd*X), out1 (sum_c wc*X via 2KB LDS partials),
//   out2 (coalesced wTb panel copy). Single-touch streams are nontemporal;
//   gathered weight panels stay cached.
// ---------------------------------------------------------------------------
__global__ __launch_bounds__(256) void main_fused(
    const float* __restrict__ Xr, const float* __restrict__ Xi,
    const int* __restrict__ ind,
    const float* __restrict__ wTc, const float* __restrict__ wTd,
    const float* __restrict__ wTb,
    float* __restrict__ out0, float* __restrict__ out1, float* __restrict__ out2) {
    __shared__ f2v part[256];
    const int b = blockIdx.x;
    const int t = threadIdx.x;
    const unsigned u = (unsigned)b * UPB + (unsigned)t;
    const bool active = (t < UPB) && (u < (unsigned)TOTAL_U);
    f2v pacc = {0.f, 0.f};
    if (active) {
        unsigned bt = u / (unsigned)UNITS_PER_BT;
        unsigned off = u - bt * (unsigned)UNITS_PER_BT;
        int dsel = ind[bt];
        f4v wd = *((const f4v*)wTd + (size_t)dsel * UNITS_PER_BT + off);
        f4v wc = *((const f4v*)wTc + (size_t)dsel * UNITS_PER_BT + off);
        f2v xr = __builtin_nontemporal_load((const f2v*)Xr + u);
        f2v xi = __builtin_nontemporal_load((const f2v*)Xi + u);
        f4v r = {wd[0] * xr[0] - wd[1] * xi[0],
                 wd[0] * xi[0] + wd[1] * xr[0],
                 wd[2] * xr[1] - wd[3] * xi[1],
                 wd[2] * xi[1] + wd[3] * xr[1]};
        __builtin_nontemporal_store(r, (f4v*)out0 + u);
        pacc[0] = (wc[0] * xr[0] - wc[1] * xi[0]) + (wc[2] * xr[1] - wc[3] * xi[1]);
        pacc[1] = (wc[0] * xi[0] + wc[1] * xr[0]) + (wc[2] * xi[1] + wc[3] * xr[1]);
    }
    part[t] = pacc;
    __syncthreads();
    if (t < FPB) {
        unsigned G = (unsigned)b * FPB + (unsigned)t;
        if (G < (unsigned)TOTAL_G) {
            f2v a0 = part[3 * t], a1 = part[3 * t + 1], a2 = part[3 * t + 2];
            f2v o1 = {a0[0] + a1[0] + a2[0], a0[1] + a1[1] + a2[1]};
            __builtin_nontemporal_store(o1, (f2v*)out1 + G);
            unsigned bt2 = G / (unsigned)Fn;
            unsigned f2_ = G - bt2 * (unsigned)Fn;
            int ds2 = ind[bt2];
            f4v wbv = *((const f4v*)wTb + (size_t)ds2 * Fn + f2_);
            __builtin_nontemporal_store(wbv, (f4v*)out2 + G);
        }
    }
}

// Fallback (no workspace): direct strided gather, per-block argmin
__global__ __launch_bounds__(256) void main_direct(
    const float* __restrict__ Xr, const float* __restrict__ Xi,
    const float* __restrict__ tdoa, const float2* __restrict__ dirs,
    const float* __restrict__ wcr, const float* __restrict__ wci,
    const float* __restrict__ wdr, const float* __restrict__ wdi,
    const float* __restrict__ wbr, const float* __restrict__ wbi,
    float2* __restrict__ out0, float2* __restrict__ out1, float2* __restrict__ out2) {
    const int bt = blockIdx.x;
    const int tid = threadIdx.x;
    __shared__ double sv[256];
    __shared__ int si[256];

    double t0 = DEG2RAD * (double)tdoa[bt * 2 + 0];
    double t1 = DEG2RAD * (double)tdoa[bt * 2 + 1];
    double ct1 = cos(t1);
    double best = 1e300;
    int bidx = 0;
    for (int d = tid; d < Dn; d += 256) {
        float2 dr = dirs[d];
        double s1 = sin(0.5 * (t1 - (double)dr.y));
        double s2 = sin(0.5 * (t0 - (double)dr.x));
        double a = s1 * s1 + ct1 * cos((double)dr.y) * (s2 * s2);
        if (a < best) { best = a; bidx = d; }
    }
    sv[tid] = best; si[tid] = bidx;
    __syncthreads();
    for (int s = 128; s > 0; s >>= 1) {
        if (tid < s) {
            double v = sv[tid + s]; int j = si[tid + s];
            if (v < sv[tid] || (v == sv[tid] && j < si[tid])) { sv[tid] = v; si[tid] = j; }
        }
        __syncthreads();
    }
    const int dsel = si[0];
    const size_t base = (size_t)bt * Fn * Cn;

    for (int f = tid; f < Fn; f += 256) {
        const int fc = f * Cn;
        float accr = 0.f, acci = 0.f;
        #pragma unroll
        for (int c = 0; c < Cn; ++c) {
            float xr = Xr[base + fc + c], xi = Xi[base + fc + c];
            size_t wo = (size_t)(c * Fn + f) * Dn + dsel;
            float a_ = wdr[wo], b_ = wdi[wo];
            out0[base + fc + c] = make_float2(a_ * xr - b_ * xi, a_ * xi + b_ * xr);
            float p = wcr[wo], q = wci[wo];
            accr += p * xr - q * xi;
            acci += p * xi + q * xr;
        }
        out1[(size_t)bt * Fn + f] = make_float2(accr, acci);
        #pragma unroll
        for (int o = 0; o < On; ++o) {
            size_t wo = (size_t)(o * Fn + f) * Dn + dsel;
            out2[((size_t)bt * Fn + f) * On + o] = make_float2(wbr[wo], wbi[wo]);
        }
    }
}

extern "C" void kernel_launch(void* const* d_in, const int* in_sizes, int n_in,
                              void* d_out, int out_size, void* d_ws, size_t ws_size,
                              hipStream_t stream) {
    const float* Xr   = (const float*)d_in[0];
    const float* Xi   = (const float*)d_in[1];
    const float* tdoa = (const float*)d_in[2];
    const float2* dirs = (const float2*)d_in[3];
    const float* wcr = (const float*)d_in[4];
    const float* wci = (const float*)d_in[5];
    const float* wdr = (const float*)d_in[6];
    const float* wdi = (const float*)d_in[7];
    const float* wbr = (const float*)d_in[8];
    const float* wbi = (const float*)d_in[9];

    float* out = (float*)d_out;

    if (ws_size >= WS_NEEDED) {
        char* ws = (char*)d_ws;
        double* tab   = (double*)ws;
        double* bttab = (double*)(ws + TAB_BYTES);
        int* ind  = (int*)(ws + TAB_BYTES + BTT_PAD);
        float* wTc = (float*)(ws + TAB_BYTES + BTT_PAD + IND_BYTES);
        float* wTd = (float*)(ws + TAB_BYTES + BTT_PAD + IND_BYTES + WTC_BYTES);
        float* wTb = (float*)(ws + TAB_BYTES + BTT_PAD + IND_BYTES + 2 * WTC_BYTES);

        build_tables<<<(Dn + BTn + 255) / 256, 256, 0, stream>>>(dirs, tdoa, tab, bttab);
        argmin_lds<<<BTn / 16, 256, 0, stream>>>(bttab, tab, ind);
        dim3 g6(Dn / 64, (Fn + 7) / 8, 2);   // 32 x 33 x 2 (wc + wd fused)
        dim3 g2(Dn / 64, (Fn + 23) / 24, 1); // 32 x 11
        transpose_w<6><<<g6, 256, 0, stream>>>(wcr, wci, (float2*)wTc,
                                               wdr, wdi, (float2*)wTd);
        transpose_w<2><<<g2, 256, 0, stream>>>(wbr, wbi, (float2*)wTb,
                                               wbr, wbi, (float2*)wTb);
        int grid = (TOTAL_U + UPB - 1) / UPB;  // 12,095
        main_fused<<<grid, 256, 0, stream>>>(Xr, Xi, ind, wTc, wTd, wTb,
                                             out, out + OUT0_F, out + OUT0_F + OUT1_F);
    } else {
        main_direct<<<BTn, 256, 0, stream>>>(Xr, Xi, tdoa, dirs,
                                             wcr, wci, wdr, wdi, wbr, wbi,
                                             (float2*)out,
                                             (float2*)(out + OUT0_F),
                                             (float2*)(out + OUT0_F + OUT1_F));
    }
}